// Round 8
// baseline (32.558 us; speedup 1.0000x reference)
//
#include <hip/hip_runtime.h>
#include <math.h>

#define D_IN_M      0.1f
#define D_OUT_M     1.0f
#define NBLK        256
#define NTHR        1024
#define NWAVE       16
#define SLOT_STRIDE 16          // floats between partial slots (64 B)

__device__ __forceinline__ float waveReduceSum(float v) {
    #pragma unroll
    for (int off = 32; off > 0; off >>= 1) v += __shfl_xor(v, off, 64);
    return v;
}

// R8: ONE worker dispatch + 4-byte memset. 256 blocks x 1024 threads.
// Counter is zeroed each launch (stream-ordered memset), so old == NBLK-1
// is a TRUE completion count (R7's modular detection raced: poisoned counter
// start made the "last" block fire at the 86th finisher). Slot write via
// device-scope atomicExch, acked (returned value consumed) before the counter
// increment; counter RMWs totally ordered at the coherence point; the real
// last block coherently reads all slots and plain-stores out[0].
__global__ __launch_bounds__(NTHR, 4)
void cae_fused_kernel(const float4* __restrict__ x,
                      const float4* __restrict__ xh,
                      const int*    __restrict__ target,
                      const float*  __restrict__ z_in,
                      const float*  __restrict__ z_out,
                      const float*  __restrict__ center_arr,
                      float* __restrict__ ws,
                      unsigned* __restrict__ counter,
                      float* __restrict__ out,
                      long n4, int B, int C, int L,
                      float invBD, float invB) {
    extern __shared__ float smc[];          // C*L normalized centers
    __shared__ float sred[NWAVE];
    __shared__ float sorth;
    __shared__ unsigned is_last;

    const int tid  = threadIdx.x;
    const int wave = tid >> 6;
    const int lane = tid & 63;
    const int epl  = L >> 6;                // 2 for L=128

    // ---- stage + normalize centers (5 KB; all blocks need them for tc) ----
    for (int c = wave; c < C; c += NWAVE) {
        const float e0 = center_arr[c * L + lane * epl + 0];
        const float e1 = center_arr[c * L + lane * epl + 1];
        const float ss = waveReduceSum(e0 * e0 + e1 * e1);
        const float inv = rsqrtf(ss);
        smc[c * L + lane * epl + 0] = e0 * inv;
        smc[c * L + lane * epl + 1] = e1 * inv;
    }
    if (tid == 0) sorth = 0.f;
    __syncthreads();

    float v = 0.f;   // this thread's scaled contribution

    // ---- MSE: contiguous per-block region, 6x-unrolled float4 pairs ----
    {
        const long per_blk = n4 / gridDim.x;                 // 12288 at 4096x3072
        const long r0 = (long)blockIdx.x * per_blk;
        const long r1 = (blockIdx.x == gridDim.x - 1) ? n4 : r0 + per_blk;
        float acc = 0.f;
        long base = r0;
        for (; base + 6L * NTHR <= r1; base += 6L * NTHR) {  // 2 iters at 4096x3072
            const long i = base + tid;
            const float4 a0 = x[i];
            const float4 a1 = x[i + NTHR];
            const float4 a2 = x[i + 2 * NTHR];
            const float4 a3 = x[i + 3 * NTHR];
            const float4 a4 = x[i + 4 * NTHR];
            const float4 a5 = x[i + 5 * NTHR];
            const float4 b0 = xh[i];
            const float4 b1 = xh[i + NTHR];
            const float4 b2 = xh[i + 2 * NTHR];
            const float4 b3 = xh[i + 3 * NTHR];
            const float4 b4 = xh[i + 4 * NTHR];
            const float4 b5 = xh[i + 5 * NTHR];
            float d;
            d = a0.x - b0.x; acc += d * d; d = a0.y - b0.y; acc += d * d;
            d = a0.z - b0.z; acc += d * d; d = a0.w - b0.w; acc += d * d;
            d = a1.x - b1.x; acc += d * d; d = a1.y - b1.y; acc += d * d;
            d = a1.z - b1.z; acc += d * d; d = a1.w - b1.w; acc += d * d;
            d = a2.x - b2.x; acc += d * d; d = a2.y - b2.y; acc += d * d;
            d = a2.z - b2.z; acc += d * d; d = a2.w - b2.w; acc += d * d;
            d = a3.x - b3.x; acc += d * d; d = a3.y - b3.y; acc += d * d;
            d = a3.z - b3.z; acc += d * d; d = a3.w - b3.w; acc += d * d;
            d = a4.x - b4.x; acc += d * d; d = a4.y - b4.y; acc += d * d;
            d = a4.z - b4.z; acc += d * d; d = a4.w - b4.w; acc += d * d;
            d = a5.x - b5.x; acc += d * d; d = a5.y - b5.y; acc += d * d;
            d = a5.z - b5.z; acc += d * d; d = a5.w - b5.w; acc += d * d;
        }
        for (long j = base + tid; j < r1; j += NTHR) {       // generic tail
            const float4 a = x[j], b = xh[j];
            float d;
            d = a.x - b.x; acc += d * d; d = a.y - b.y; acc += d * d;
            d = a.z - b.z; acc += d * d; d = a.w - b.w; acc += d * d;
        }
        v = acc * invBD;
    }

    // ---- triplet-center + outlier: one wave per row (256*16 = 4096) ----
    const int row = blockIdx.x * NWAVE + wave;
    if (row < B) {
        const float zi0 = z_in[row * L + lane * epl + 0];
        const float zi1 = z_in[row * L + lane * epl + 1];
        const int tgt = target[row];
        float pos = 0.f, neg = INFINITY;
        for (int c = 0; c < C; ++c) {
            const float d0 = zi0 - smc[c * L + lane * epl + 0];
            const float d1 = zi1 - smc[c * L + lane * epl + 1];
            const float d2 = waveReduceSum(d0 * d0 + d1 * d1);
            const float dist = sqrtf(d2);
            if (c == tgt) pos = dist;
            else          neg = fminf(neg, dist);
        }
        const float zo0 = z_out[row * L + lane * epl + 0];
        const float zo1 = z_out[row * L + lane * epl + 1];
        const float zo2 = waveReduceSum(zo0 * zo0 + zo1 * zo1);
        if (lane == 0) {
            const float tc = fmaxf(pos + D_IN_M - neg, 0.f);
            const float ol = fmaxf(D_OUT_M - sqrtf(zo2), 0.f);
            v += (tc + ol) * invB;
        }
    }

    // ---- orthogonality (block 0 only; waves 0..C-1 one gram row each) ----
    if (blockIdx.x == 0) {
        float part = 0.f;
        for (int r = wave; r < C; r += NWAVE) {
            const float ra0 = smc[r * L + lane * epl + 0];
            const float ra1 = smc[r * L + lane * epl + 1];
            for (int cc = 0; cc < C; ++cc) {
                const float d = waveReduceSum(
                    ra0 * smc[cc * L + lane * epl + 0] +
                    ra1 * smc[cc * L + lane * epl + 1]);
                const float t = d - (cc == r ? 1.f : 0.f);
                part += t * t;
            }
        }
        if (lane == 0) atomicAdd(&sorth, part);
    }

    // ---- block reduce -> slot (atomicExch) -> zero-based done-counter ----
    v = waveReduceSum(v);
    if (lane == 0) sred[wave] = v;
    __syncthreads();
    if (tid == 0) {
        float s = 0.f;
        #pragma unroll
        for (int w = 0; w < NWAVE; ++w) s += sred[w];
        if (blockIdx.x == 0) s += sqrtf(sorth);
        const float old = atomicExch(&ws[(long)blockIdx.x * SLOT_STRIDE], s);
        asm volatile("" :: "v"(old));   // consume -> exch acked before counter
        const unsigned oc = atomicAdd(counter, 1u);
        is_last = (oc == NBLK - 1u) ? 1u : 0u;   // true count: counter starts 0
    }
    __syncthreads();

    // ---- exactly the LAST block reduces the slots ----
    if (is_last) {
        float s = 0.f;
        for (int i = tid; i < NBLK; i += NTHR)
            s += atomicAdd(&ws[(long)i * SLOT_STRIDE], 0.0f);  // coherent read
        s = waveReduceSum(s);
        if (lane == 0) sred[wave] = s;
        __syncthreads();
        if (tid == 0) {
            float t = 0.f;
            #pragma unroll
            for (int w = 0; w < NWAVE; ++w) t += sred[w];
            out[0] = t;
        }
    }
}

extern "C" void kernel_launch(void* const* d_in, const int* in_sizes, int n_in,
                              void* d_out, int out_size, void* d_ws, size_t ws_size,
                              hipStream_t stream) {
    const float* x          = (const float*)d_in[0];
    const float* x_hat      = (const float*)d_in[1];
    const int*   target     = (const int*)d_in[2];
    const float* z_in       = (const float*)d_in[3];
    const float* z_out      = (const float*)d_in[4];
    const float* center_arr = (const float*)d_in[5];
    float* out = (float*)d_out;
    float* ws  = (float*)d_ws;

    const int B = in_sizes[2];
    const int D = in_sizes[0] / B;
    const int L = in_sizes[3] / B;
    const int C = in_sizes[5] / L;
    const long n4 = (long)B * D / 4;

    unsigned* counter = (unsigned*)(ws + (long)NBLK * SLOT_STRIDE);

    // zero ONLY the 4-byte counter each launch (stream-ordered, capture-safe)
    hipMemsetAsync(counter, 0, sizeof(unsigned), stream);

    cae_fused_kernel<<<NBLK, NTHR, C * L * sizeof(float), stream>>>(
        (const float4*)x, (const float4*)x_hat, target, z_in, z_out, center_arr,
        ws, counter, out, n4, B, C, L, 1.f / ((float)B * D), 1.f / (float)B);
}

// Round 10
// 30.006 us; speedup vs baseline: 1.0851x; 1.0851x over previous
//
#include <hip/hip_runtime.h>
#include <math.h>

#define D_IN_M      0.1f
#define D_OUT_M     1.0f
#define NBLK        2048
#define NTHR        256
#define SLOT_STRIDE 16          // floats between partial slots (64 B)

__device__ __forceinline__ float waveReduceSum(float v) {
    #pragma unroll
    for (int off = 32; off > 0; off >>= 1) v += __shfl_xor(v, off, 64);
    return v;
}

// Issue one 16B load the compiler cannot sink or split.
#define GLOAD(dst, p) \
    asm volatile("global_load_dwordx4 %0, %1, off" : "=v"(dst) : "v"(p))

// R10: R9 with a compilable drain: bare s_waitcnt vmcnt(0) asm + sched_barrier(0)
// (rule-18 idiom) instead of 12 tied asm operands. 12 loads in flight per wave
// vs the compiler's 2-3 at VGPR=36.
__global__ __launch_bounds__(NTHR, 2)
void cae_fused_kernel(const float4* __restrict__ x,
                      const float4* __restrict__ xh,
                      const int*    __restrict__ target,
                      const float*  __restrict__ z_in,
                      const float*  __restrict__ z_out,
                      const float*  __restrict__ center_arr,
                      float* __restrict__ ws,
                      long n4, int B, int C, int L,
                      float invBD, float invB) {
    extern __shared__ float smc[];          // C*L normalized centers
    __shared__ float sred[4];
    __shared__ float sorth;

    const int tid  = threadIdx.x;
    const int wave = tid >> 6;
    const int lane = tid & 63;
    const int epl  = L >> 6;                // 2 for L=128
    const long cpb = 6L * NTHR;             // float4s per block chunk

    // ---- issue first chunk's 12 loads as an un-sinkable asm batch ----
    const long i0 = (long)blockIdx.x * cpb;
    const bool full0 = (i0 + cpb <= n4);    // always true at 4096x3072
    float4 a0, a1, a2, a3, a4, a5, b0, b1, b2, b3, b4, b5;
    if (full0) {
        const long i = i0 + tid;
        GLOAD(a0, x + i);            GLOAD(a1, x + i + NTHR);
        GLOAD(a2, x + i + 2 * NTHR); GLOAD(a3, x + i + 3 * NTHR);
        GLOAD(a4, x + i + 4 * NTHR); GLOAD(a5, x + i + 5 * NTHR);
        GLOAD(b0, xh + i);           GLOAD(b1, xh + i + NTHR);
        GLOAD(b2, xh + i + 2 * NTHR);GLOAD(b3, xh + i + 3 * NTHR);
        GLOAD(b4, xh + i + 4 * NTHR);GLOAD(b5, xh + i + 5 * NTHR);
    }

    // ---- center staging: only blocks that carry tc rows ----
    const int nrowblk = (B + 3) >> 2;
    const bool needs_centers = (blockIdx.x < (unsigned)nrowblk);
    if (needs_centers) {
        for (int c = wave; c < C; c += 4) {
            const float e0 = center_arr[c * L + lane * epl + 0];
            const float e1 = center_arr[c * L + lane * epl + 1];
            const float ss = waveReduceSum(e0 * e0 + e1 * e1);
            const float inv = rsqrtf(ss);
            smc[c * L + lane * epl + 0] = e0 * inv;
            smc[c * L + lane * epl + 1] = e1 * inv;
        }
        if (tid == 0) sorth = 0.f;
        __syncthreads();
    }

    float v = 0.f;   // this thread's scaled contribution

    // ---- drain the batch, consume MSE ----
    {
        float acc = 0.f;
        if (full0) {
            // rule-18 idiom: manual drain + full scheduler fence so no
            // consumer of the asm-produced values is hoisted above the wait.
            asm volatile("s_waitcnt vmcnt(0)" ::: "memory");
            __builtin_amdgcn_sched_barrier(0);
            float d;
            d = a0.x - b0.x; acc += d * d; d = a0.y - b0.y; acc += d * d;
            d = a0.z - b0.z; acc += d * d; d = a0.w - b0.w; acc += d * d;
            d = a1.x - b1.x; acc += d * d; d = a1.y - b1.y; acc += d * d;
            d = a1.z - b1.z; acc += d * d; d = a1.w - b1.w; acc += d * d;
            d = a2.x - b2.x; acc += d * d; d = a2.y - b2.y; acc += d * d;
            d = a2.z - b2.z; acc += d * d; d = a2.w - b2.w; acc += d * d;
            d = a3.x - b3.x; acc += d * d; d = a3.y - b3.y; acc += d * d;
            d = a3.z - b3.z; acc += d * d; d = a3.w - b3.w; acc += d * d;
            d = a4.x - b4.x; acc += d * d; d = a4.y - b4.y; acc += d * d;
            d = a4.z - b4.z; acc += d * d; d = a4.w - b4.w; acc += d * d;
            d = a5.x - b5.x; acc += d * d; d = a5.y - b5.y; acc += d * d;
            d = a5.z - b5.z; acc += d * d; d = a5.w - b5.w; acc += d * d;
        } else {
            for (long j = i0 + tid; j < n4; j += NTHR) {
                const float4 a = x[j], b = xh[j];
                float d;
                d = a.x - b.x; acc += d * d; d = a.y - b.y; acc += d * d;
                d = a.z - b.z; acc += d * d; d = a.w - b.w; acc += d * d;
            }
        }
        // further chunks (not taken at 4096x3072 with grid 2048)
        for (long j0 = i0 + (long)gridDim.x * cpb; j0 < n4; j0 += (long)gridDim.x * cpb) {
            for (long j = j0 + tid; j < n4 && j < j0 + cpb; j += NTHR) {
                const float4 a = x[j], b = xh[j];
                float d;
                d = a.x - b.x; acc += d * d; d = a.y - b.y; acc += d * d;
                d = a.z - b.z; acc += d * d; d = a.w - b.w; acc += d * d;
            }
        }
        v = acc * invBD;
    }

    // ---- triplet-center + outlier: one wave per row ----
    const int row = blockIdx.x * 4 + wave;
    if (row < B) {
        const float zi0 = z_in[row * L + lane * epl + 0];
        const float zi1 = z_in[row * L + lane * epl + 1];
        const int tgt = target[row];
        float pos = 0.f, neg = INFINITY;
        for (int c = 0; c < C; ++c) {
            const float d0 = zi0 - smc[c * L + lane * epl + 0];
            const float d1 = zi1 - smc[c * L + lane * epl + 1];
            const float d2 = waveReduceSum(d0 * d0 + d1 * d1);
            const float dist = sqrtf(d2);
            if (c == tgt) pos = dist;
            else          neg = fminf(neg, dist);
        }
        const float zo0 = z_out[row * L + lane * epl + 0];
        const float zo1 = z_out[row * L + lane * epl + 1];
        const float zo2 = waveReduceSum(zo0 * zo0 + zo1 * zo1);
        if (lane == 0) {
            const float tc = fmaxf(pos + D_IN_M - neg, 0.f);
            const float ol = fmaxf(D_OUT_M - sqrtf(zo2), 0.f);
            v += (tc + ol) * invB;
        }
    }

    // ---- orthogonality (block 0 only) ----
    if (blockIdx.x == 0) {
        float part = 0.f;
        for (int r = wave; r < C; r += 4) {
            const float ra0 = smc[r * L + lane * epl + 0];
            const float ra1 = smc[r * L + lane * epl + 1];
            for (int cc = 0; cc < C; ++cc) {
                const float d = waveReduceSum(
                    ra0 * smc[cc * L + lane * epl + 0] +
                    ra1 * smc[cc * L + lane * epl + 1]);
                const float t = d - (cc == r ? 1.f : 0.f);
                part += t * t;
            }
        }
        if (lane == 0) atomicAdd(&sorth, part);
    }

    // ---- block reduce + plain store to private 64B-spaced slot ----
    v = waveReduceSum(v);
    if (lane == 0) sred[wave] = v;
    __syncthreads();
    if (tid == 0) {
        float s = sred[0] + sred[1] + sred[2] + sred[3];
        if (blockIdx.x == 0) s += sqrtf(sorth);
        ws[(long)blockIdx.x * SLOT_STRIDE] = s;
    }
}

__global__ void reduce_kernel(const float* __restrict__ ws,
                              float* __restrict__ out, int nblk) {
    const int tid = threadIdx.x;
    float s = 0.f;
    for (int i = tid; i < nblk; i += 256) s += ws[(long)i * SLOT_STRIDE];
    s = waveReduceSum(s);
    __shared__ float sm[4];
    const int wave = tid >> 6, lane = tid & 63;
    if (lane == 0) sm[wave] = s;
    __syncthreads();
    if (tid == 0) out[0] = sm[0] + sm[1] + sm[2] + sm[3];
}

extern "C" void kernel_launch(void* const* d_in, const int* in_sizes, int n_in,
                              void* d_out, int out_size, void* d_ws, size_t ws_size,
                              hipStream_t stream) {
    const float* x          = (const float*)d_in[0];
    const float* x_hat      = (const float*)d_in[1];
    const int*   target     = (const int*)d_in[2];
    const float* z_in       = (const float*)d_in[3];
    const float* z_out      = (const float*)d_in[4];
    const float* center_arr = (const float*)d_in[5];
    float* out = (float*)d_out;
    float* ws  = (float*)d_ws;

    const int B = in_sizes[2];
    const int D = in_sizes[0] / B;
    const int L = in_sizes[3] / B;
    const int C = in_sizes[5] / L;
    const long n4 = (long)B * D / 4;

    cae_fused_kernel<<<NBLK, NTHR, C * L * sizeof(float), stream>>>(
        (const float4*)x, (const float4*)x_hat, target, z_in, z_out, center_arr,
        ws, n4, B, C, L, 1.f / ((float)B * D), 1.f / (float)B);

    reduce_kernel<<<1, 256, 0, stream>>>(ws, out, NBLK);
}